// Round 3
// baseline (562.280 us; speedup 1.0000x reference)
//
#include <hip/hip_runtime.h>

#define M_DIM 8192
#define N_DIM 4096
#define K_DIM 4096

typedef __attribute__((ext_vector_type(8))) __bf16 bf16x8;
typedef __attribute__((ext_vector_type(4))) __bf16 bf16x4;
typedef __attribute__((ext_vector_type(4))) float floatx4;

// ---------- async global->LDS, 16B per lane (wave-uniform LDS base) ----------
__device__ __forceinline__ void async_copy16(const void* g, void* l) {
    __builtin_amdgcn_global_load_lds(
        (const __attribute__((address_space(1))) void*)g,
        (__attribute__((address_space(3))) void*)l,
        16, 0, 0);
}

// 32-bit LDS byte address for inline-asm ds_read (compiler-invisible LDS read)
__device__ __forceinline__ unsigned lds_addr(const void* p) {
    return (unsigned)(unsigned long long)(const __attribute__((address_space(3))) void*)p;
}
// ds_read_b128 with compile-time offset immediate (zero per-tile address VALU)
#define DSR(dst, addr, OFF) \
    asm volatile("ds_read_b128 %0, %1 offset:" #OFF : "=v"(dst) : "v"(addr))

// ---------- deterministic reductions (fp64) ----------
__device__ __forceinline__ double wave_reduce_d(double v) {
    #pragma unroll
    for (int o = 32; o > 0; o >>= 1) v += __shfl_down(v, o, 64);
    return v;
}
__device__ __forceinline__ unsigned wave_reduce_u(unsigned v) {
    #pragma unroll
    for (int o = 32; o > 0; o >>= 1) v += __shfl_down(v, o, 64);
    return v;
}

// K1 (fused): blocks [0,2048) -> partial sums of |W|; blocks [2048,10240) -> x fp32->bf16
__global__ __launch_bounds__(256) void k_pre(const float4* __restrict__ w4,
                                             double* __restrict__ part,
                                             const float4* __restrict__ x4,
                                             bf16x4* __restrict__ xb) {
    const int tid = threadIdx.x;
    if (blockIdx.x < 2048) {
        int idx = blockIdx.x * 256 + tid;
        double s = 0.0;
        #pragma unroll
        for (int it = 0; it < 8; ++it) {
            float4 v = w4[idx + it * (2048 * 256)];
            s += (double)fabsf(v.x) + (double)fabsf(v.y) +
                 (double)fabsf(v.z) + (double)fabsf(v.w);
        }
        s = wave_reduce_d(s);
        __shared__ double sm[4];
        if ((tid & 63) == 0) sm[tid >> 6] = s;
        __syncthreads();
        if (tid == 0) part[blockIdx.x] = sm[0] + sm[1] + sm[2] + sm[3];
    } else {
        int idx = (blockIdx.x - 2048) * 256 + tid;
        #pragma unroll
        for (int it = 0; it < 4; ++it) {
            int i = idx + it * (8192 * 256);
            float4 v = x4[i];
            bf16x4 o;
            o[0] = (__bf16)v.x; o[1] = (__bf16)v.y;
            o[2] = (__bf16)v.z; o[3] = (__bf16)v.w;
            xb[i] = o;
        }
    }
}

// K2: block-redundant delta from part[2048]; quantize; masked partial sums.
// Per-element math BIT-IDENTICAL to the passing kernel (f64 delta/compare).
__global__ __launch_bounds__(256) void k_quant(const float4* __restrict__ w4,
                                               bf16x4* __restrict__ tern,
                                               const double* __restrict__ part,
                                               double* __restrict__ scal,
                                               double* __restrict__ pm,
                                               unsigned* __restrict__ pc) {
    const int tid = threadIdx.x;
    double s = 0.0;
    #pragma unroll
    for (int i = 0; i < 8; ++i) s += part[tid + i * 256];
    s = wave_reduce_d(s);
    __shared__ double sm[4];
    if ((tid & 63) == 0) sm[tid >> 6] = s;
    __syncthreads();
    const double mean = (sm[0] + sm[1] + sm[2] + sm[3]) * (1.0 / 16777216.0);
    const double delta = 0.7 * mean;
    if (blockIdx.x == 0 && tid == 0) scal[0] = mean;

    int idx = blockIdx.x * 256 + tid;
    double msum = 0.0;
    unsigned cnt = 0;
    #pragma unroll
    for (int it = 0; it < 8; ++it) {
        int i = idx + it * (2048 * 256);
        float4 v = w4[i];
        float e[4] = {v.x, v.y, v.z, v.w};
        bf16x4 o;
        #pragma unroll
        for (int c = 0; c < 4; ++c) {
            float wv = e[c];
            float t = ((double)wv > delta) ? 1.0f
                    : (((double)wv < -delta) ? -1.0f : 0.0f);
            if (t != 0.0f) { msum += (double)fabsf(wv); cnt++; }
            o[c] = (__bf16)t;
        }
        tern[i] = o;
    }
    msum = wave_reduce_d(msum);
    cnt  = wave_reduce_u(cnt);
    __shared__ double smd[4];
    __shared__ unsigned smu[4];
    if ((tid & 63) == 0) { smd[tid >> 6] = msum; smu[tid >> 6] = cnt; }
    __syncthreads();
    if (tid == 0) {
        pm[blockIdx.x] = smd[0] + smd[1] + smd[2] + smd[3];
        pc[blockIdx.x] = smu[0] + smu[1] + smu[2] + smu[3];
    }
}

// ---------- GEMM: C[m][n] = alpha * sum_k A[m][k]*B[n][k] + bias[n] ----------
// Round-0 geometry (256x128 tile, 4 waves, per-wave 128x64 -> 2 blocks/CU =
// 2 independent barrier domains) + round-2 machinery (3-deep LDS ring, counted
// vmcnt(12) never 0 in-loop, inline-asm ds_read_b128 with offset immediates,
// lgkmcnt(4)/(0) split, rule-#18 sched_barrier, setprio around MFMA).
// LDS chunk layout + XOR swizzle identical to round-0 (measured 0 conflicts).
__global__ __launch_bounds__(256, 2) void ternary_gemm(
    const __bf16* __restrict__ A,    // M x K (x in bf16)
    const __bf16* __restrict__ B,    // N x K (ternary in bf16)
    const float*  __restrict__ bias, // N
    const double* __restrict__ scal, // [0] = mean|w| fallback
    const double* __restrict__ pm,   // 2048 masked partial sums
    const unsigned* __restrict__ pc, // 2048 masked partial counts
    float* __restrict__ C)           // M x N
{
    __shared__ __attribute__((aligned(128))) __bf16 As[3][8192];  // 48 KB
    __shared__ __attribute__((aligned(128))) __bf16 Bs[3][4096];  // 24 KB
    __shared__ double smd[4];
    __shared__ unsigned smu[4];

    const int tid  = threadIdx.x;
    const int w    = tid >> 6;
    const int lane = tid & 63;
    const int quad = lane >> 4;
    const int l16  = lane & 15;
    const int wr = w >> 1;   // row half: 128 rows
    const int wc = w & 1;    // col half: 64 cols

    // bijective XCD swizzle (1024 % 8 == 0): 128 consecutive ids per XCD
    const int id = (blockIdx.x & 7) * 128 + (blockIdx.x >> 3);
    const int br = id >> 5;  // 0..31 M tile (256)
    const int bc = id & 31;  // 0..31 N tile (128)

    // staging: chunk = 16 rows x 32 cols (1 KB). A: 16 chunks, B: 8 chunks.
    // wave w: A chunks 4w..4w+3, B chunks 2w..2w+1.
    // XOR swizzle: LDS pos (lane&3) holds global octet (lane&3)^((srow>>1)&3).
    const int srow = lane >> 2;
    const int scol = ((lane & 3) ^ ((srow >> 1) & 3)) * 8;

    const __bf16* gA[4];
    const __bf16* gB[2];
    #pragma unroll
    for (int t = 0; t < 4; ++t)
        gA[t] = A + (size_t)(br * 256 + (w * 4 + t) * 16 + srow) * K_DIM + scol;
    #pragma unroll
    for (int t = 0; t < 2; ++t)
        gB[t] = B + (size_t)(bc * 128 + (w * 2 + t) * 16 + srow) * K_DIM + scol;

    floatx4 acc[8][4] = {};

    // fragment read: octet for (quad, row l16) sits at position quad^((l16>>1)&3)
    const int swz   = (quad ^ ((l16 >> 1) & 3)) * 8;
    const int a_off = (wr * 128 + l16) * 32 + swz;
    const int b_off = (wc * 64 + l16) * 32 + swz;

    // per-ring-slot LDS base addresses (compile-time offsets ride on these)
    const unsigned aS0 = lds_addr(&As[0][0]) + (unsigned)(a_off * 2);
    const unsigned aS1 = aS0 + 16384;
    const unsigned aS2 = aS0 + 32768;
    const unsigned bS0 = lds_addr(&Bs[0][0]) + (unsigned)(b_off * 2);
    const unsigned bS1 = bS0 + 8192;
    const unsigned bS2 = bS0 + 16384;

#define STAGE(stg, SLOT) do {                                              \
        const int _so = (stg) * 32;                                        \
        async_copy16(gA[0] + _so, &As[SLOT][(w * 4 + 0) * 512]);           \
        async_copy16(gA[1] + _so, &As[SLOT][(w * 4 + 1) * 512]);           \
        async_copy16(gA[2] + _so, &As[SLOT][(w * 4 + 2) * 512]);           \
        async_copy16(gA[3] + _so, &As[SLOT][(w * 4 + 3) * 512]);           \
        async_copy16(gB[0] + _so, &Bs[SLOT][(w * 2 + 0) * 512]);           \
        async_copy16(gB[1] + _so, &Bs[SLOT][(w * 2 + 1) * 512]);           \
    } while (0)

#define TILE(stg, SSLOT, AB, BB, VMN, DO_STAGE) do {                           \
        if (DO_STAGE) STAGE(stg, SSLOT);                                       \
        asm volatile("s_waitcnt vmcnt(" #VMN ")" ::: "memory");                \
        __builtin_amdgcn_s_barrier();                                          \
        bf16x8 _a[8], _b[4];                                                   \
        DSR(_a[0], AB, 0);    DSR(_a[1], AB, 1024);                            \
        DSR(_a[2], AB, 2048); DSR(_a[3], AB, 3072);                            \
        DSR(_b[0], BB, 0);    DSR(_b[1], BB, 1024);                            \
        DSR(_b[2], BB, 2048); DSR(_b[3], BB, 3072);                            \
        DSR(_a[4], AB, 4096); DSR(_a[5], AB, 5120);                            \
        DSR(_a[6], AB, 6144); DSR(_a[7], AB, 7168);                            \
        asm volatile("s_waitcnt lgkmcnt(4)" ::: "memory");                     \
        __builtin_amdgcn_sched_barrier(0);                                     \
        __builtin_amdgcn_s_setprio(1);                                         \
        _Pragma("unroll")                                                      \
        for (int i = 0; i < 4; ++i)                                            \
            _Pragma("unroll")                                                  \
            for (int j = 0; j < 4; ++j)                                        \
                acc[i][j] = __builtin_amdgcn_mfma_f32_16x16x32_bf16(           \
                    _a[i], _b[j], acc[i][j], 0, 0, 0);                         \
        __builtin_amdgcn_s_setprio(0);                                         \
        asm volatile("s_waitcnt lgkmcnt(0)" ::: "memory");                     \
        __builtin_amdgcn_sched_barrier(0);                                     \
        __builtin_amdgcn_s_setprio(1);                                         \
        _Pragma("unroll")                                                      \
        for (int i = 0; i < 4; ++i)                                            \
            _Pragma("unroll")                                                  \
            for (int j = 0; j < 4; ++j)                                        \
                acc[4 + i][j] = __builtin_amdgcn_mfma_f32_16x16x32_bf16(       \
                    _a[4 + i], _b[j], acc[4 + i][j], 0, 0, 0);                 \
        __builtin_amdgcn_s_setprio(0);                                         \
        __builtin_amdgcn_sched_barrier(0);                                     \
        __builtin_amdgcn_s_barrier();                                          \
    } while (0)

    // prologue: stage tiles 0,1 (12 loads per wave in flight)
    STAGE(0, 0);
    STAGE(1, 1);

    // main loop: 128 K-tiles; stage kt+2 while computing kt; vmcnt never 0
    for (int kt = 0; kt < 126; kt += 3) {
        TILE(kt + 2, 2, aS0, bS0, 12, true);   // tile kt   (slot 0)
        TILE(kt + 3, 0, aS1, bS1, 12, true);   // tile kt+1 (slot 1)
        TILE(kt + 4, 1, aS2, bS2, 12, true);   // tile kt+2 (slot 2)
    }
    TILE(0, 0, aS0, bS0, 6, false);            // tile 126 (slot 0), 6 left
    TILE(0, 0, aS1, bS1, 0, false);            // tile 127 (slot 1), drain

#undef TILE
#undef STAGE

    // block-redundant alpha reduce (deterministic, identical in every block)
    double s = 0.0; unsigned c = 0;
    #pragma unroll
    for (int i = 0; i < 8; ++i) { s += pm[tid + i * 256]; c += pc[tid + i * 256]; }
    s = wave_reduce_d(s);
    c = wave_reduce_u(c);
    if ((tid & 63) == 0) { smd[tid >> 6] = s; smu[tid >> 6] = c; }
    __syncthreads();
    const double ms = smd[0] + smd[1] + smd[2] + smd[3];
    const unsigned ct = smu[0] + smu[1] + smu[2] + smu[3];
    const float alpha = (float)(ct > 0 ? ms / (double)ct : scal[0]);

    float bv[4];
    #pragma unroll
    for (int j = 0; j < 4; ++j)
        bv[j] = bias[bc * 128 + wc * 64 + j * 16 + l16];

    // C/D layout (16x16x32): col = lane&15, row = quad*4 + reg
    #pragma unroll
    for (int i = 0; i < 8; ++i) {
        const int row0 = br * 256 + wr * 128 + i * 16 + quad * 4;
        #pragma unroll
        for (int j = 0; j < 4; ++j) {
            const int col = bc * 128 + wc * 64 + j * 16 + l16;
            #pragma unroll
            for (int r = 0; r < 4; ++r)
                C[(size_t)(row0 + r) * N_DIM + col] = acc[i][j][r] * alpha + bv[j];
        }
    }
}

extern "C" void kernel_launch(void* const* d_in, const int* in_sizes, int n_in,
                              void* d_out, int out_size, void* d_ws, size_t ws_size,
                              hipStream_t stream) {
    const float* x    = (const float*)d_in[0];  // (8192, 4096) fp32
    const float* w    = (const float*)d_in[1];  // (4096, 4096) fp32
    const float* bias = (const float*)d_in[2];  // (4096,) fp32
    float* out = (float*)d_out;                 // (8192, 4096) fp32

    char* ws = (char*)d_ws;
    double*   d_scal = (double*)ws;               // [0] = mean|w|
    double*   part   = (double*)(ws + 64);        // 2048 doubles
    double*   pm     = (double*)(ws + 16448);     // 2048 doubles
    unsigned* pc     = (unsigned*)(ws + 32832);   // 2048 uints
    __bf16*   xb     = (__bf16*)(ws + 65536);                                   // 64 MB
    __bf16*   tern   = (__bf16*)(ws + 65536 + (size_t)M_DIM * K_DIM * 2);       // 32 MB

    k_pre<<<10240, 256, 0, stream>>>((const float4*)w, part, (const float4*)x, (bf16x4*)xb);
    k_quant<<<2048, 256, 0, stream>>>((const float4*)w, (bf16x4*)tern, part, d_scal, pm, pc);

    ternary_gemm<<<1024, 256, 0, stream>>>(xb, tern, bias, d_scal, pm, pc, out);
}